// Round 5
// baseline (573.475 us; speedup 1.0000x reference)
//
#include <hip/hip_runtime.h>
#include <hip/hip_cooperative_groups.h>
#include <math.h>

namespace cg = cooperative_groups;

#define N_NODES 50000
#define M_ITEMS 5000
#define D_FEAT 64
#define D_HID 32
#define D_EMB 64
#define N_EDGES 1200000
#define BATCH 4096
#define CAP 80          // Poisson(24) tail: P(deg>=80) ~ 4e-18
#define GRID 256
#define BLK 512
#define GT (GRID * BLK) // 131072 threads

struct Params {
    const int* x; const float* node_x; const int* src; const int* dst;
    const float* rating; const float* Wenc; const float* benc;
    const float* Wdec; const float* bdec;
    const float* Wl1; const float* bl1; const float* Wr1;
    const float* Wl2; const float* bl2; const float* Wr2;
    int* cursor; int* slot; float* y1; float* h; float* emb; float* WencT;
    float* out;
};

__device__ __forceinline__ float sigmoidf_(float z) {
    return 1.0f / (1.0f + __expf(-z));
}

__global__ __launch_bounds__(BLK, 2)
void k_all(Params p) {
    __shared__ float smem[12800];   // 50 KB, unioned across phases
    __shared__ int nsS[16];
    const int tid  = threadIdx.x;
    const int bid  = blockIdx.x;
    const int gtid = bid * BLK + tid;
    const int lane = tid & 63;
    const int wv   = tid >> 6;
    cg::grid_group grid = cg::this_grid();

    // ================= P0: cursor zero + WencT transpose + y1 ============
    for (int i = gtid; i < N_NODES; i += GT) p.cursor[i] = 0;

    {   // transpose Wenc [64,5000] -> WencT [5000,64] via LDS tiles 64x128
        float* tileL = smem + 2048;            // 64*129 floats
        for (int t = bid; t < 40; t += GRID) {
            int m0 = t * 128;
            for (int j = tid; j < 8192; j += BLK) {
                int e = j >> 7, c = j & 127;
                if (m0 + c < M_ITEMS)
                    tileL[e * 129 + c] = p.Wenc[(size_t)e * M_ITEMS + m0 + c];
            }
            __syncthreads();
            for (int j = tid; j < 8192; j += BLK) {
                int ep = j & 63, mp = j >> 6;
                if (m0 + mp < M_ITEMS)
                    p.WencT[(size_t)(m0 + mp) * 64 + ep] = tileL[ep * 129 + mp];
            }
            __syncthreads();
        }
    }
    {   // y1 = node_x @ Wl1^T   [50000,32]
        float* wsT = smem;                     // [64][32] k-major
        for (int j = tid; j < D_FEAT * D_HID; j += BLK) {
            int c = j >> 6, k = j & 63;        // Wl1[c][k]
            wsT[k * D_HID + c] = p.Wl1[j];
        }
        __syncthreads();
        for (int idx = gtid; idx < N_NODES * D_HID; idx += GT) {
            int r = idx >> 5, c = idx & 31;
            const float* xp = p.node_x + (size_t)r * D_FEAT;
            float s = 0.f;
#pragma unroll
            for (int k = 0; k < D_FEAT; k += 4) {
                float4 xv = *reinterpret_cast<const float4*>(xp + k);
                s = fmaf(xv.x, wsT[(k + 0) * D_HID + c], s);
                s = fmaf(xv.y, wsT[(k + 1) * D_HID + c], s);
                s = fmaf(xv.z, wsT[(k + 2) * D_HID + c], s);
                s = fmaf(xv.w, wsT[(k + 3) * D_HID + c], s);
            }
            p.y1[idx] = s;
        }
    }
    grid.sync();

    // ================= P1: CSR fill =======================================
    for (int e = gtid; e < N_EDGES; e += GT) {
        int dn = p.dst[e];
        int pos = atomicAdd(&p.cursor[dn], 1);
        if (pos < CAP) p.slot[(size_t)dn * CAP + pos] = p.src[e];
    }
    grid.sync();

    // ================= P2: h = relu(gather(y1)/deg + bl1 + node_x@Wr1^T) ==
    {
        float* wt = smem;                      // 2048
        float* xs = smem + 2048;               // 512
        for (int j = tid; j < D_HID * D_FEAT; j += BLK) {
            int c = j >> 6, k = j & 63;        // Wr1[c][k]
            wt[k * D_HID + c] = p.Wr1[j];
        }
        __syncthreads();
        const int k32 = lane & 31, hi = lane >> 5;
        const int w0 = __builtin_amdgcn_readfirstlane(bid * 8 + wv);
        for (int n = w0; n < N_NODES; n += GT / 64) {
            const int dgf = p.cursor[n];
            const int dg = min(dgf, CAP);
            const int* sl = p.slot + (size_t)n * CAP;
            float a0 = 0.f, a1 = 0.f, a2 = 0.f, a3 = 0.f;
            int t = 0;
            for (; t + 8 <= dg; t += 8) {
                int e0 = sl[t + 0], e1 = sl[t + 1], e2 = sl[t + 2], e3 = sl[t + 3];
                int e4 = sl[t + 4], e5 = sl[t + 5], e6 = sl[t + 6], e7 = sl[t + 7];
                int n0 = hi ? e1 : e0;
                int n1 = hi ? e3 : e2;
                int n2 = hi ? e5 : e4;
                int n3 = hi ? e7 : e6;
                a0 += p.y1[(size_t)n0 * D_HID + k32];
                a1 += p.y1[(size_t)n1 * D_HID + k32];
                a2 += p.y1[(size_t)n2 * D_HID + k32];
                a3 += p.y1[(size_t)n3 * D_HID + k32];
            }
            for (; t < dg; t += 2) {
                int e0 = sl[t];
                int e1 = (t + 1 < dg) ? sl[t + 1] : e0;
                int nb = hi ? e1 : e0;
                if (t + hi < dg) a0 += p.y1[(size_t)nb * D_HID + k32];
            }
            float g = (a0 + a1) + (a2 + a3);
            g += __shfl(g, lane ^ 32, 64);     // lanes<32 hold feature sums
            xs[wv * 64 + lane] = p.node_x[(size_t)n * D_FEAT + lane];
            if (lane < 32) {
                float s = g / fmaxf((float)dgf, 1.f) + p.bl1[k32];
#pragma unroll
                for (int kg = 0; kg < 16; ++kg) {
                    float4 xv = *reinterpret_cast<const float4*>(&xs[wv * 64 + kg * 4]);
                    s = fmaf(xv.x, wt[(4 * kg + 0) * D_HID + k32], s);
                    s = fmaf(xv.y, wt[(4 * kg + 1) * D_HID + k32], s);
                    s = fmaf(xv.z, wt[(4 * kg + 2) * D_HID + k32], s);
                    s = fmaf(xv.w, wt[(4 * kg + 3) * D_HID + k32], s);
                }
                p.h[(size_t)n * D_HID + k32] = fmaxf(s, 0.f);
            }
        }
    }
    grid.sync();

    // ================= P3: enc (coalesced LDS staging) + combine ==========
    {
        float* rlds = smem;            // [16][500] = 8000 floats
        float* red  = smem;            // [8][16][64] = 8192 (union, after chunks)
        float* wl2t = smem + 8192;     // 2048
        float* wr2t = smem + 10240;    // 2048
        float* aggl = smem + 12288;    // 8*32
        float* hl   = smem + 12544;    // 8*32
        if (tid < 16) nsS[tid] = p.x[bid * 16 + tid];
        for (int j = tid; j < D_EMB * D_HID; j += BLK) {
            int e = j >> 5, k = j & 31;        // W[e][k]
            wl2t[k * D_EMB + e] = p.Wl2[j];
            wr2t[k * D_EMB + e] = p.Wr2[j];
        }
        __syncthreads();
        int nh[16];
#pragma unroll
        for (int i = 0; i < 16; ++i)
            nh[i] = __builtin_amdgcn_readfirstlane(nsS[i]);
        float acc[16];
#pragma unroll
        for (int i = 0; i < 16; ++i) acc[i] = 0.f;

        for (int ch = 0; ch < 10; ++ch) {
            // coalesced stage: 16 rows x 500 cols (2000 float4s)
            for (int j4 = tid; j4 < 2000; j4 += BLK) {
                int row = j4 / 125, c4 = j4 % 125;
                float4 v = *reinterpret_cast<const float4*>(
                    p.rating + (size_t)nh[row] * M_ITEMS + ch * 500 + c4 * 4);
                *reinterpret_cast<float4*>(&rlds[row * 500 + c4 * 4]) = v;
            }
            __syncthreads();
            for (int g = wv; g < 125; g += 8) {
                int ml = g * 4, gm = ch * 500 + ml;
                float w0 = p.WencT[(size_t)(gm + 0) * 64 + lane];
                float w1 = p.WencT[(size_t)(gm + 1) * 64 + lane];
                float w2 = p.WencT[(size_t)(gm + 2) * 64 + lane];
                float w3 = p.WencT[(size_t)(gm + 3) * 64 + lane];
#pragma unroll
                for (int r = 0; r < 16; ++r) {
                    float4 rv = *reinterpret_cast<const float4*>(&rlds[r * 500 + ml]);
                    acc[r] = fmaf(rv.x, w0, acc[r]);
                    acc[r] = fmaf(rv.y, w1, acc[r]);
                    acc[r] = fmaf(rv.z, w2, acc[r]);
                    acc[r] = fmaf(rv.w, w3, acc[r]);
                }
            }
            __syncthreads();
        }
        // cross-wave reduce (red unions rlds; last sync above protects it)
#pragma unroll
        for (int r = 0; r < 16; ++r) red[(wv * 16 + r) * 64 + lane] = acc[r];
        __syncthreads();

        const int k32 = lane & 31, hi = lane >> 5;
#pragma unroll
        for (int half = 0; half < 2; ++half) {
            const int r = 2 * wv + half;
            const int nu = nh[r];
            float ae = p.benc[lane];
#pragma unroll
            for (int w = 0; w < 8; ++w) ae += red[(w * 16 + r) * 64 + lane];
            // layer-2 gather over h (32-wide), 2 nbrs per instr
            const int dgf = p.cursor[nu];
            const int dg = min(dgf, CAP);
            const int* sl = p.slot + (size_t)nu * CAP;
            float a0 = 0.f, a1 = 0.f, a2 = 0.f, a3 = 0.f;
            int t = 0;
            for (; t + 8 <= dg; t += 8) {
                int e0 = sl[t + 0], e1 = sl[t + 1], e2 = sl[t + 2], e3 = sl[t + 3];
                int e4 = sl[t + 4], e5 = sl[t + 5], e6 = sl[t + 6], e7 = sl[t + 7];
                int n0 = hi ? e1 : e0;
                int n1 = hi ? e3 : e2;
                int n2 = hi ? e5 : e4;
                int n3 = hi ? e7 : e6;
                a0 += p.h[(size_t)n0 * D_HID + k32];
                a1 += p.h[(size_t)n1 * D_HID + k32];
                a2 += p.h[(size_t)n2 * D_HID + k32];
                a3 += p.h[(size_t)n3 * D_HID + k32];
            }
            for (; t < dg; t += 2) {
                int e0 = sl[t];
                int e1 = (t + 1 < dg) ? sl[t + 1] : e0;
                int nb = hi ? e1 : e0;
                if (t + hi < dg) a0 += p.h[(size_t)nb * D_HID + k32];
            }
            float g = (a0 + a1) + (a2 + a3);
            g += __shfl(g, lane ^ 32, 64);
            if (lane < 32) {
                aggl[wv * 32 + k32] = g / fmaxf((float)dgf, 1.f);
                hl[wv * 32 + k32] = p.h[(size_t)nu * D_HID + k32];
            }
            float ge = p.bl2[lane];
#pragma unroll
            for (int k = 0; k < D_HID; ++k)
                ge = fmaf(aggl[wv * 32 + k], wl2t[k * D_EMB + lane], ge);
#pragma unroll
            for (int k = 0; k < D_HID; ++k)
                ge = fmaf(hl[wv * 32 + k], wr2t[k * D_EMB + lane], ge);
            p.emb[(size_t)(bid * 16 + r) * D_EMB + lane] = sigmoidf_(ge + ae);
        }
    }
    grid.sync();

    // ================= P4: out = sigmoid(emb @ Wdec^T + bdec) =============
    {
        float* tl = smem;   // 32*64
        for (int t = bid; t < 2560; t += GRID) {     // exactly 10 tiles/block
            int mb = t % 20, bb = t / 20;
            __syncthreads();
            for (int j = tid; j < 2048; j += BLK)
                tl[j] = p.emb[(size_t)bb * 2048 + j];
            __syncthreads();
            int m = mb * 256 + (tid & 255);
            int rh = (tid >> 8) * 16;
            if (m < M_ITEMS) {
                float acc2[16];
#pragma unroll
                for (int i = 0; i < 16; ++i) acc2[i] = 0.f;
                const float* wp = p.Wdec + (size_t)m * 64;
#pragma unroll
                for (int k = 0; k < 64; k += 4) {
                    float4 w = *reinterpret_cast<const float4*>(wp + k);
#pragma unroll
                    for (int i = 0; i < 16; ++i) {
                        acc2[i] = fmaf(w.x, tl[(rh + i) * 64 + k + 0], acc2[i]);
                        acc2[i] = fmaf(w.y, tl[(rh + i) * 64 + k + 1], acc2[i]);
                        acc2[i] = fmaf(w.z, tl[(rh + i) * 64 + k + 2], acc2[i]);
                        acc2[i] = fmaf(w.w, tl[(rh + i) * 64 + k + 3], acc2[i]);
                    }
                }
                float bv = p.bdec[m];
#pragma unroll
                for (int i = 0; i < 16; ++i)
                    p.out[(size_t)(bb * 32 + rh + i) * M_ITEMS + m] =
                        sigmoidf_(acc2[i] + bv);
            }
        }
    }
}

extern "C" void kernel_launch(void* const* d_in, const int* in_sizes, int n_in,
                              void* d_out, int out_size, void* d_ws, size_t ws_size,
                              hipStream_t stream) {
    const int* ei = (const int*)d_in[2];

    char* w = (char*)d_ws;
    int*   cursor = (int*)w;   w += (size_t)N_NODES * 4;
    int*   slot   = (int*)w;   w += (size_t)N_NODES * CAP * 4;
    float* y1     = (float*)w; w += (size_t)N_NODES * D_HID * 4;
    float* h      = (float*)w; w += (size_t)N_NODES * D_HID * 4;
    float* emb    = (float*)w; w += (size_t)BATCH * D_EMB * 4;
    float* WencT  = (float*)w; w += (size_t)M_ITEMS * D_EMB * 4;

    Params prm;
    prm.x      = (const int*)d_in[0];
    prm.node_x = (const float*)d_in[1];
    prm.src    = ei;
    prm.dst    = ei + N_EDGES;
    prm.rating = (const float*)d_in[3];
    prm.Wenc   = (const float*)d_in[4];
    prm.benc   = (const float*)d_in[5];
    prm.Wdec   = (const float*)d_in[6];
    prm.bdec   = (const float*)d_in[7];
    prm.Wl1    = (const float*)d_in[8];
    prm.bl1    = (const float*)d_in[9];
    prm.Wr1    = (const float*)d_in[10];
    prm.Wl2    = (const float*)d_in[11];
    prm.bl2    = (const float*)d_in[12];
    prm.Wr2    = (const float*)d_in[13];
    prm.cursor = cursor; prm.slot = slot; prm.y1 = y1; prm.h = h;
    prm.emb = emb; prm.WencT = WencT;
    prm.out = (float*)d_out;

    void* args[] = { &prm };
    hipLaunchCooperativeKernel((void*)k_all, dim3(GRID), dim3(BLK),
                               args, 0, stream);
}

// Round 6
// 296.500 us; speedup vs baseline: 1.9341x; 1.9341x over previous
//
#include <hip/hip_runtime.h>
#include <math.h>

#define N_NODES 50000
#define M_ITEMS 5000
#define D_FEAT 64
#define D_HID 32
#define D_EMB 64
#define N_EDGES 1200000
#define BATCH 4096
#define CAP 80      // Poisson(24) tail: P(deg>=80) ~ 4e-18
#define KCH 10      // encoder K-chunks
#define KW  500     // cols per chunk

__device__ __forceinline__ float sigmoidf_(float z) {
    return 1.0f / (1.0f + __expf(-z));
}

// ---------------- mega1: CSR fill + Wenc transpose + y1 GEMV (one dispatch)
#define FILL_BLOCKS  ((N_EDGES + 255) / 256)                 // 4688
#define XW_BLOCKS    ((N_NODES * D_HID + 255) / 256)         // 6250
#define TR_BLOCKS    ((D_EMB * M_ITEMS + 255) / 256)         // 1250

__global__ __launch_bounds__(256)
void k_mega1(const int* __restrict__ src, const int* __restrict__ dst,
             int* __restrict__ cursor, int* __restrict__ slot,
             const float* __restrict__ Wenc, float* __restrict__ WencT,
             const float* __restrict__ node_x, const float* __restrict__ Wl1,
             float* __restrict__ y1) {
    __shared__ float wsT[D_FEAT * D_HID];
    const int bid = blockIdx.x;
    if (bid < FILL_BLOCKS) {
        int e = bid * 256 + threadIdx.x;
        if (e < N_EDGES) {
            int dn = dst[e];
            int pos = atomicAdd(&cursor[dn], 1);
            if (pos < CAP) slot[(size_t)dn * CAP + pos] = src[e];
        }
        return;
    }
    if (bid < FILL_BLOCKS + XW_BLOCKS) {
        for (int j = threadIdx.x; j < D_FEAT * D_HID; j += 256) {
            int c = j >> 6, k = j & 63;          // Wl1[c,k]
            wsT[k * D_HID + c] = Wl1[j];
        }
        __syncthreads();
        int idx = (bid - FILL_BLOCKS) * 256 + threadIdx.x;
        if (idx >= N_NODES * D_HID) return;
        int r = idx >> 5, c = idx & 31;
        const float* xp = node_x + (size_t)r * D_FEAT;
        float s = 0.f;
#pragma unroll
        for (int k = 0; k < D_FEAT; k += 4) {
            float4 xv = *reinterpret_cast<const float4*>(xp + k);
            s = fmaf(xv.x, wsT[(k + 0) * D_HID + c], s);
            s = fmaf(xv.y, wsT[(k + 1) * D_HID + c], s);
            s = fmaf(xv.z, wsT[(k + 2) * D_HID + c], s);
            s = fmaf(xv.w, wsT[(k + 3) * D_HID + c], s);
        }
        y1[idx] = s;
        return;
    }
    {   // W_enc [64,5000] -> W_encT [5000,64]
        int idx = (bid - FILL_BLOCKS - XW_BLOCKS) * 256 + threadIdx.x;
        if (idx >= D_EMB * M_ITEMS) return;
        int e = idx & 63, m = idx >> 6;
        WencT[idx] = Wenc[(size_t)e * M_ITEMS + m];
    }
}

// ---------------- node1: 8 nodes/block (32 lanes each), slot idx via shuffle
__device__ __forceinline__ int pick4_32(int s0, int s1, int s2, int s3, int j) {
    int v = (j < 32) ? s0 : (j < 64) ? s1 : (j < 96) ? s2 : s3;
    return __shfl(v, j & 31, 32);
}

__global__ __launch_bounds__(256)
void k_node1(const float* __restrict__ node_x, const float* __restrict__ y1,
             const int* __restrict__ cursor, const int* __restrict__ slot,
             const float* __restrict__ Wr1, const float* __restrict__ bl1,
             float* __restrict__ h) {
    __shared__ float wt[D_FEAT * D_HID];   // Wr1 k-major
    for (int j = threadIdx.x; j < D_HID * D_FEAT; j += 256) {
        int c = j >> 6, k = j & 63;        // Wr1[c,k]
        wt[k * D_HID + c] = Wr1[j];
    }
    __syncthreads();
    const int lane = threadIdx.x & 31;
    const int n = blockIdx.x * 8 + (threadIdx.x >> 5);   // 50000 = 6250*8
    const int dgf = cursor[n];
    const int dg = min(dgf, CAP);
    const int* sl = slot + (size_t)n * CAP;
    int s0 = (lane < dg) ? sl[lane] : 0;
    int s1 = (32 + lane < dg) ? sl[32 + lane] : 0;
    int s2 = (64 + lane < dg) ? sl[64 + lane] : 0;
    int s3 = 0;   // CAP=80 <= 96
    float g0 = 0.f, g1 = 0.f, g2 = 0.f, g3 = 0.f;
    int j = 0;
    for (; j + 4 <= dg; j += 4) {
        int a = pick4_32(s0, s1, s2, s3, j);
        int b = pick4_32(s0, s1, s2, s3, j + 1);
        int c = pick4_32(s0, s1, s2, s3, j + 2);
        int d = pick4_32(s0, s1, s2, s3, j + 3);
        g0 += y1[(size_t)a * D_HID + lane];
        g1 += y1[(size_t)b * D_HID + lane];
        g2 += y1[(size_t)c * D_HID + lane];
        g3 += y1[(size_t)d * D_HID + lane];
    }
    for (; j < dg; ++j)
        g0 += y1[(size_t)pick4_32(s0, s1, s2, s3, j) * D_HID + lane];
    float g = ((g0 + g1) + (g2 + g3)) / fmaxf((float)dgf, 1.f) + bl1[lane];
    const float* xp = node_x + (size_t)n * D_FEAT;
    float s = 0.f;
#pragma unroll
    for (int k = 0; k < D_FEAT; k += 4) {
        float4 xv = *reinterpret_cast<const float4*>(xp + k);
        s = fmaf(xv.x, wt[(k + 0) * D_HID + lane], s);
        s = fmaf(xv.y, wt[(k + 1) * D_HID + lane], s);
        s = fmaf(xv.z, wt[(k + 2) * D_HID + lane], s);
        s = fmaf(xv.w, wt[(k + 3) * D_HID + lane], s);
    }
    h[(size_t)n * D_HID + lane] = fmaxf(g + s, 0.f);
}

// ---------------- enc partials: grid (256 rowblocks, 10 kchunks), 512 thr.
// Stage 16 rows x 500 cols coalesced into LDS, 8 waves split the 125 m-groups,
// LDS cross-wave reduce, write part[ky][row][64].
__global__ __launch_bounds__(512)
void k_enc_part(const int* __restrict__ x, const float* __restrict__ rating,
                const float* __restrict__ WencT, float* __restrict__ part) {
    __shared__ float sm[8192];             // 32 KB: stage 16*500, then red 8*16*64
    __shared__ int ns[16];
    const int tid = threadIdx.x, lane = tid & 63, wv = tid >> 6;
    const int rb = blockIdx.x * 16;
    const int ky = blockIdx.y;
    if (tid < 16) ns[tid] = x[rb + tid];
    __syncthreads();
    int nh[16];
#pragma unroll
    for (int i = 0; i < 16; ++i)
        nh[i] = __builtin_amdgcn_readfirstlane(ns[i]);
    // coalesced stage: 2000 float4s (16 rows x 125)
    for (int j4 = tid; j4 < 2000; j4 += 512) {
        int row = j4 / 125, c4 = j4 - row * 125;
        float4 v = *reinterpret_cast<const float4*>(
            rating + (size_t)nh[row] * M_ITEMS + ky * KW + c4 * 4);
        *reinterpret_cast<float4*>(&sm[row * KW + c4 * 4]) = v;
    }
    __syncthreads();
    float acc[16];
#pragma unroll
    for (int i = 0; i < 16; ++i) acc[i] = 0.f;
    for (int g = wv; g < 125; g += 8) {
        int ml = g * 4, gm = ky * KW + ml;
        float w0 = WencT[(size_t)(gm + 0) * 64 + lane];
        float w1 = WencT[(size_t)(gm + 1) * 64 + lane];
        float w2 = WencT[(size_t)(gm + 2) * 64 + lane];
        float w3 = WencT[(size_t)(gm + 3) * 64 + lane];
#pragma unroll
        for (int r = 0; r < 16; ++r) {
            float4 rv = *reinterpret_cast<const float4*>(&sm[r * KW + ml]);
            acc[r] = fmaf(rv.x, w0, acc[r]);
            acc[r] = fmaf(rv.y, w1, acc[r]);
            acc[r] = fmaf(rv.z, w2, acc[r]);
            acc[r] = fmaf(rv.w, w3, acc[r]);
        }
    }
    __syncthreads();                        // staging reads done; reuse sm
#pragma unroll
    for (int r = 0; r < 16; ++r) sm[(wv * 16 + r) * 64 + lane] = acc[r];
    __syncthreads();
#pragma unroll
    for (int half = 0; half < 2; ++half) {
        int r = wv * 2 + half;
        float s = 0.f;
#pragma unroll
        for (int w = 0; w < 8; ++w) s += sm[(w * 16 + r) * 64 + lane];
        part[((size_t)ky * BATCH + rb + r) * 64 + lane] = s;
    }
}

// ---------------- comb: sum 10 partials + layer-2 graph terms + sigmoid.
// 8 rows/block (1 wave each), 512 blocks.
__global__ __launch_bounds__(512)
void k_comb(const int* __restrict__ x, const float* __restrict__ part,
            const float* __restrict__ benc, const int* __restrict__ cursor,
            const int* __restrict__ slot, const float* __restrict__ h,
            const float* __restrict__ Wl2, const float* __restrict__ bl2,
            const float* __restrict__ Wr2, float* __restrict__ emb) {
    __shared__ float wl2t[D_HID * D_EMB];
    __shared__ float wr2t[D_HID * D_EMB];
    __shared__ float aggl[8][D_HID];
    __shared__ float hl[8][D_HID];
    __shared__ int ns[8];
    const int tid = threadIdx.x, lane = tid & 63, wv = tid >> 6;
    const int rb = blockIdx.x * 8;
    if (tid < 8) ns[tid] = x[rb + tid];
    for (int j = tid; j < D_EMB * D_HID; j += 512) {
        int e = j >> 5, k = j & 31;        // W[e,k]
        wl2t[k * D_EMB + e] = Wl2[j];
        wr2t[k * D_EMB + e] = Wr2[j];
    }
    __syncthreads();
    const int row = rb + wv;
    const int node = __builtin_amdgcn_readfirstlane(ns[wv]);
    float ae = benc[lane];
#pragma unroll
    for (int ky = 0; ky < KCH; ++ky)
        ae += part[((size_t)ky * BATCH + row) * 64 + lane];
    // layer-2 gather over h (32-wide), 2 neighbors per instruction
    const int k32 = lane & 31, hi = lane >> 5;
    const int dgf = cursor[node];
    const int dg = min(dgf, CAP);
    const int* sl = slot + (size_t)node * CAP;
    float a0 = 0.f, a1 = 0.f, a2 = 0.f, a3 = 0.f;
    int t = 0;
    for (; t + 8 <= dg; t += 8) {
        int e0 = sl[t + 0], e1 = sl[t + 1], e2 = sl[t + 2], e3 = sl[t + 3];
        int e4 = sl[t + 4], e5 = sl[t + 5], e6 = sl[t + 6], e7 = sl[t + 7];
        int n0 = hi ? e1 : e0;
        int n1 = hi ? e3 : e2;
        int n2 = hi ? e5 : e4;
        int n3 = hi ? e7 : e6;
        a0 += h[(size_t)n0 * D_HID + k32];
        a1 += h[(size_t)n1 * D_HID + k32];
        a2 += h[(size_t)n2 * D_HID + k32];
        a3 += h[(size_t)n3 * D_HID + k32];
    }
    for (; t < dg; t += 2) {
        int e0 = sl[t];
        int e1 = (t + 1 < dg) ? sl[t + 1] : e0;
        int nb = hi ? e1 : e0;
        if (t + hi < dg) a0 += h[(size_t)nb * D_HID + k32];
    }
    float g = (a0 + a1) + (a2 + a3);
    g += __shfl(g, lane ^ 32, 64);
    if (lane < 32) {
        aggl[wv][k32] = g / fmaxf((float)dgf, 1.f);
        hl[wv][k32] = h[(size_t)node * D_HID + k32];
    }
    float ge = bl2[lane];
#pragma unroll
    for (int k = 0; k < D_HID; ++k)
        ge = fmaf(aggl[wv][k], wl2t[k * D_EMB + lane], ge);
#pragma unroll
    for (int k = 0; k < D_HID; ++k)
        ge = fmaf(hl[wv][k], wr2t[k * D_EMB + lane], ge);
    emb[(size_t)row * D_EMB + lane] = sigmoidf_(ge + ae);
}

// ---------------- dec: 2560 blocks x 256 thr; emb via wave-uniform loads
__global__ __launch_bounds__(256)
void k_dec(const float* __restrict__ emb, const float* __restrict__ Wdec,
           const float* __restrict__ bdec, float* __restrict__ out) {
    const int tid = threadIdx.x;
    const int b0 = blockIdx.y * 32;
    const int m = blockIdx.x * 256 + tid;
    if (m >= M_ITEMS) return;
    const float* ep = emb + (size_t)b0 * 64;   // wave-uniform base
    float acc[32];
#pragma unroll
    for (int i = 0; i < 32; ++i) acc[i] = 0.f;
    const float* wp = Wdec + (size_t)m * 64;
#pragma unroll
    for (int k = 0; k < 64; k += 4) {
        float4 w = *reinterpret_cast<const float4*>(&wp[k]);
#pragma unroll
        for (int i = 0; i < 32; ++i) {
            float4 e4 = *reinterpret_cast<const float4*>(ep + i * 64 + k);
            acc[i] = fmaf(w.x, e4.x, acc[i]);
            acc[i] = fmaf(w.y, e4.y, acc[i]);
            acc[i] = fmaf(w.z, e4.z, acc[i]);
            acc[i] = fmaf(w.w, e4.w, acc[i]);
        }
    }
    float bb = bdec[m];
#pragma unroll
    for (int i = 0; i < 32; ++i)
        out[(size_t)(b0 + i) * M_ITEMS + m] = sigmoidf_(acc[i] + bb);
}

extern "C" void kernel_launch(void* const* d_in, const int* in_sizes, int n_in,
                              void* d_out, int out_size, void* d_ws, size_t ws_size,
                              hipStream_t stream) {
    const int*   x      = (const int*)d_in[0];
    const float* node_x = (const float*)d_in[1];
    const int*   ei     = (const int*)d_in[2];
    const float* rating = (const float*)d_in[3];
    const float* Wenc   = (const float*)d_in[4];
    const float* benc   = (const float*)d_in[5];
    const float* Wdec   = (const float*)d_in[6];
    const float* bdec   = (const float*)d_in[7];
    const float* Wl1    = (const float*)d_in[8];
    const float* bl1    = (const float*)d_in[9];
    const float* Wr1    = (const float*)d_in[10];
    const float* Wl2    = (const float*)d_in[11];
    const float* bl2    = (const float*)d_in[12];
    const float* Wr2    = (const float*)d_in[13];
    const int* src = ei;
    const int* dst = ei + N_EDGES;

    char* w = (char*)d_ws;
    int*   cursor = (int*)w;   w += (size_t)N_NODES * 4;
    int*   slot   = (int*)w;   w += (size_t)N_NODES * CAP * 4;
    float* y1     = (float*)w; w += (size_t)N_NODES * D_HID * 4;
    float* h      = (float*)w; w += (size_t)N_NODES * D_HID * 4;
    float* emb    = (float*)w; w += (size_t)BATCH * D_EMB * 4;
    float* WencT  = (float*)w; w += (size_t)M_ITEMS * D_EMB * 4;
    float* part   = (float*)w; w += (size_t)KCH * BATCH * D_EMB * 4;

    hipMemsetAsync(cursor, 0, (size_t)N_NODES * 4, stream);

    k_mega1<<<FILL_BLOCKS + XW_BLOCKS + TR_BLOCKS, 256, 0, stream>>>(
        src, dst, cursor, slot, Wenc, WencT, node_x, Wl1, y1);
    k_node1<<<N_NODES / 8, 256, 0, stream>>>(
        node_x, y1, cursor, slot, Wr1, bl1, h);
    dim3 genc(BATCH / 16, KCH);
    k_enc_part<<<genc, 512, 0, stream>>>(x, rating, WencT, part);
    k_comb<<<BATCH / 8, 512, 0, stream>>>(
        x, part, benc, cursor, slot, h, Wl2, bl2, Wr2, emb);
    dim3 gdec((M_ITEMS + 255) / 256, BATCH / 32);
    k_dec<<<gdec, 256, 0, stream>>>(emb, Wdec, bdec, (float*)d_out);
}